// Round 10
// baseline (227.244 us; speedup 1.0000x reference)
//
#include <hip/hip_runtime.h>

typedef unsigned short u16;
typedef unsigned int u32;
typedef __attribute__((ext_vector_type(8))) short bfrag_t;   // 8 bf16 (4 VGPRs)
typedef __attribute__((ext_vector_type(4))) float accfrag_t; // 4 fp32
typedef __attribute__((ext_vector_type(4))) u32 u32x4;

// ---------- bf16 helpers ----------
__device__ __forceinline__ u16 f2b(float f) {
    u32 u = __float_as_uint(f);
    u32 r = (u + 0x7FFFu + ((u >> 16) & 1u)) >> 16;
    return (u16)r;
}
// pack 2 f32 -> 2 bf16 in one instruction (lo -> bits[15:0], hi -> bits[31:16])
__device__ __forceinline__ u32 pkbf16(float lo, float hi) {
    u32 r;
    asm("v_cvt_pk_bf16_f32 %0, %1, %2" : "=v"(r) : "v"(lo), "v"(hi));
    return r;
}
__device__ __forceinline__ float blo(u32 v) { return __uint_as_float(v << 16); }
__device__ __forceinline__ float bhi(u32 v) { return __uint_as_float(v & 0xffff0000u); }

// ---------- async global->LDS, 16B per lane ----------
__device__ __forceinline__ void load16(const u16* g, u16* l) {
    __builtin_amdgcn_global_load_lds(
        (__attribute__((address_space(1))) void*)(u16*)g,
        (__attribute__((address_space(3))) void*)l,
        16, 0, 0);
}

// ============================================================
// Merged prep: range dispatch, 1153 blocks. (identical since R2; R8
// probe measured its marginal cost at ~2 us — not a lever.)
// ============================================================
__global__ __launch_bounds__(256) void k_prep(
    const float* __restrict__ x, const float* __restrict__ W1,
    const float* __restrict__ W2, const float* __restrict__ W3,
    const float* __restrict__ b2, u16* __restrict__ xtp,
    u16* __restrict__ W1f, u16* __restrict__ W2f,
    u16* __restrict__ W3f, float* __restrict__ b2p) {
    __shared__ __align__(16) char smem[29184];
    const int bid = blockIdx.x;
    const int tid = threadIdx.x;
    if (bid < 928) {             // ---- xtp ----
        const int b = bid / 116;
        const int r = bid - b * 116;
        const int hp = r >> 1;           // 0..57
        const int ch = r & 1;            // c-half: c0 = ch*128
        u16* rowbase = xtp + (size_t)(b * 58 + hp) * 58 * 256;
        if (hp == 0 || hp == 57) {       // zero border row (ch==0 does it all)
            if (ch == 0) {
                u32* p = (u32*)rowbase;
                for (int i = tid; i < 58 * 128; i += 256) p[i] = 0;
            }
            return;
        }
        float* lds = (float*)smem;       // [cl:128][w:57]  (odd stride: conflict-free)
        const int h = hp - 1;
        const int c0 = ch * 128;
        const float* xb = x + (size_t)(b * 256 + c0) * 3136 + h * 56;
#pragma unroll
        for (int it = 0; it < 7; ++it) {
            const int idx = it * 256 + tid;
            const int cl = idx / 14;
            const int f4 = idx - cl * 14;
            const float4 v = *(const float4*)(xb + (size_t)cl * 3136 + f4 * 4);
            float* d = lds + cl * 57 + f4 * 4;
            d[0] = v.x; d[1] = v.y; d[2] = v.z; d[3] = v.w;
        }
        __syncthreads();
        u32* orow = (u32*)rowbase;
        const int cp = tid & 63;
        const int wg = tid >> 6;
        const float* l0p = lds + (2 * cp) * 57;
        const float* l1p = lds + (2 * cp + 1) * 57;
#pragma unroll
        for (int it = 0; it < 15; ++it) {
            const int wp = it * 4 + wg;  // 0..59
            if (wp < 58) {
                u32 val = 0;
                if (wp >= 1 && wp <= 56) val = pkbf16(l0p[wp - 1], l1p[wp - 1]);
                orow[wp * 128 + ch * 64 + cp] = val;
            }
        }
    } else if (bid < 1072) {     // ---- W1 / W3 pack ----
        int b = bid - 928;
        const float* in = b < 72 ? W1 : W3;
        u16* out = b < 72 ? W1f : W3f;
        if (b >= 72) b -= 72;
        const int rrp = b >> 3;          // 0..8
        const int cg = b & 7;            // c-group of 32
        u16* lds1 = (u16*)smem;          // [q:32][n:256]
#pragma unroll
        for (int cc = 0; cc < 32; ++cc) {
            int d = (cg * 32 + cc) * 9 + rrp;
            lds1[cc * 256 + tid] = f2b(in[d * 256 + tid]);
        }
        __syncthreads();
        const int kc72 = rrp * 8 + cg;
#pragma unroll
        for (int s = 0; s < 32; ++s) {
            const int w = s >> 2;
            const int o = (s & 3) * 256 + tid;    // 0..1023 within [j][lane][e]
            const int e = o & 7;
            const int ln = (o >> 3) & 63;
            const int j = o >> 9;
            const int n = w * 32 + j * 16 + (ln & 15);
            const int q = (ln >> 4) * 8 + e;
            out[(w * 72 + kc72) * 1024 + o] = lds1[q * 256 + n];
        }
    } else if (bid < 1144) {     // ---- W2 pack ----
        const int b = bid - 1072;
        const int rr = b >> 3;
        const int w = b & 7;
        u16* lds2 = (u16*)smem;          // [k:256][dloc:32]
#pragma unroll
        for (int s = 0; s < 32; ++s) {
            int li = s * 256 + tid;
            int k = li >> 5, dloc = li & 31;
            lds2[k * 32 + dloc] = f2b(W2[k * 2304 + (w * 32 + dloc) * 9 + rr]);
        }
        __syncthreads();
        u16* ob = W2f + (rr * 8 + w) * 8192;
#pragma unroll
        for (int s = 0; s < 32; ++s) {
            const int o = s * 256 + tid;          // 0..8191
            const int e = o & 7;
            const int ln = (o >> 3) & 63;
            const int j = (o >> 9) & 1;
            const int kc = o >> 10;
            const int k = kc * 32 + (ln >> 4) * 8 + e;
            const int dloc = j * 16 + (ln & 15);
            ob[o] = lds2[k * 32 + dloc];
        }
    } else {                     // ---- b2 permute ----
        int idx = (bid - 1144) * 256 + tid;
        if (idx < 2304) b2p[idx] = b2[(idx & 255) * 9 + (idx >> 8)];
    }
}

// ============================================================
// Fused kernel v9 = v8 structure (1x8 split, swizzled LDS 0-conflict,
// wave=kc slab ownership, merged [2b;2a] region, setprio) on a
// BALANCED MIXED GRID: 512 blocks = 8 XCDs x (4 big(64-row) + 60
// small(48-row)); per XCD = 3136 rows = one batch image (XCD-local xtp).
// All 512 CU-slots filled (2 blocks/CU exactly); big blocks at p<32 so
// their same-CU partner (p+256, empirical round-robin) is small ->
// max CU load 112 rows vs v8's 128 (-12.5%). Downside bounded: worst
// pairing = 128 rows = v8 status quo.
// Variable rows via uniform NI in {3,4} i-tile guards (static indices).
// ============================================================
__global__ __launch_bounds__(512, 4) void k_fused(
    const u16* __restrict__ xtp, const u16* __restrict__ W1f,
    const u16* __restrict__ W2f, const u16* __restrict__ W3f,
    const float* __restrict__ b1, const float* __restrict__ b2p,
    const float* __restrict__ b3, float* __restrict__ out) {
    __shared__ __align__(16) u16 As[16384];  // 32KB: t-slab buf0, then h1 [kc:8][row:64][slot:4][8]
    __shared__ __align__(16) u16 Us[16384];  // 32KB: t-slab buf1, then s/u same layout

    const int tid = threadIdx.x;
    const int wave = tid >> 6;
    const int lane = tid & 63;
    const int fr = lane & 15;
    const int fq = lane >> 4;

    // ---- mixed-grid work assignment ----
    const int p = blockIdx.x;
    const int xcd = p & 7;           // empirical: consecutive blocks round-robin XCDs
    const int k = p >> 3;            // 0..63 within XCD
    const int big = (k < 4) ? 1 : 0; // p<32 are the 64-row blocks
    const int NI = big ? 4 : 3;      // i-tiles (16 rows each)
    const int l0 = xcd * 3136 + (big ? k * 64 : 256 + (k - 4) * 48);

    // ---- wave=kc ownership: wave w stages/owns slab w ----
    const int swz = (lane & 3) ^ ((lane >> 3) & 3);
    int roffs[4], ldst[4];
#pragma unroll
    for (int q = 0; q < 4; ++q) {
        const int row = (q < 4 ? q : 0) * 16 + (lane >> 2);
        const int l = l0 + (q < NI ? row : (lane >> 2));   // q>=NI: safe dummy
        const int b = l / 3136;
        const int rem = l - b * 3136;
        const int h = rem / 56;
        const int w = rem - h * 56;
        roffs[q] = ((b * 58 + h + 1) * 58 + (w + 1)) * 256 + wave * 32 + swz * 8;
        ldst[q] = wave * 2048 + (q * 64 + lane) * 8;
    }
    // A-frag read offset within a kc-slab: row=i*16+fr, slot=fq^((fr>>1)&3)
    const int aoff = fr * 32 + ((fq ^ ((fr >> 1) & 3)) * 8);
    auto shiftOf = [](int rr) { return ((rr / 3 - 1) * 58 + (rr % 3) - 1) * 256; };
    auto stage = [&](u16* buf, int shift) {
#pragma unroll
        for (int q = 0; q < 4; ++q)
            if (q < NI) load16(xtp + roffs[q] + shift, buf + ldst[q]);
    };
    // swizzled epilogue u32-write index (u16 units) within slab `wave`
    auto ewidx = [&](int i, int j, int r) {
        const int row = i * 16 + fq * 4 + r;
        const int sl = (j * 2 + (fr >> 3)) ^ ((fq * 2 + (r >> 1)) & 3);
        return row * 32 + sl * 8 + (fr & 7);
    };

    accfrag_t acc[4][2], accO[4][2];
#pragma unroll
    for (int i = 0; i < 4; ++i)
#pragma unroll
        for (int j = 0; j < 2; ++j) {
            acc[i][j] = (accfrag_t)0.f;
            accO[i][j] = (accfrag_t)0.f;
        }

    // ---------------- phase 1: h1 = relu(t @ W1 + b1), double-buffered ----
    const u16* w1p = W1f + wave * 73728 + lane * 8;
    stage(As, shiftOf(0));
    for (int rr = 0; rr < 9; ++rr) {
        u16* cur = (rr & 1) ? Us : As;
        u16* nxt = (rr & 1) ? As : Us;
        __syncthreads();   // cur slab visible (and nxt's readers from rr-1 done)
        if (rr < 8) stage(nxt, shiftOf(rr + 1));   // in flight during MFMA
        __builtin_amdgcn_s_setprio(1);
#pragma unroll
        for (int kc = 0; kc < 8; ++kc) {
            bfrag_t bf[2], af[4];
#pragma unroll
            for (int j = 0; j < 2; ++j)
                bf[j] = *(const bfrag_t*)(w1p + ((rr * 8 + kc) * 2 + j) * 512);
#pragma unroll
            for (int i = 0; i < 4; ++i)
                if (i < NI)
                    af[i] = *(const bfrag_t*)(cur + kc * 2048 + i * 512 + aoff);
#pragma unroll
            for (int i = 0; i < 4; ++i)
                if (i < NI)
#pragma unroll
                    for (int j = 0; j < 2; ++j)
                        acc[i][j] = __builtin_amdgcn_mfma_f32_16x16x32_bf16(
                            af[i], bf[j], acc[i][j], 0, 0, 0);
        }
        __builtin_amdgcn_s_setprio(0);
    }
    // h1 epilogue: relu, pair-pack (cvt_pk), into As slab `wave` (swizzled)
    __syncthreads();
#pragma unroll
    for (int i = 0; i < 4; ++i) {
        if (i >= NI) continue;
#pragma unroll
        for (int j = 0; j < 2; ++j) {
            const float bv = b1[wave * 32 + j * 16 + fr];
#pragma unroll
            for (int r = 0; r < 4; ++r) {
                float v = acc[i][j][r] + bv;
                v = v > 0.f ? v : 0.f;
                const float vh = __shfl_down(v, 1);
                if (!(lane & 1))
                    *(u32*)&As[wave * 2048 + ewidx(i, j, r)] = pkbf16(v, vh);
            }
        }
    }
    __syncthreads();  // h1 visible to all waves

    // ---------------- phase 2: pipelined per-rr ----------------
    // per rr: [2b(rr-1); 2a(rr)]  barrier  [sigmoid; u(same-wave)]  barrier
    const u16* w3p = W3f + wave * 73728 + lane * 8;
    const u16* w2base = W2f + (wave)*8192 + lane * 8;  // + rr*8*8192 per rr
    for (int rr = 0; rr < 9; ++rr) {
        // 2b for rr-1 (reads Us; no Us writes since last barrier)
        __builtin_amdgcn_s_setprio(1);
        if (rr > 0) {
#pragma unroll
            for (int kc = 0; kc < 8; ++kc) {
                bfrag_t bf[2], af[4];
#pragma unroll
                for (int j = 0; j < 2; ++j)
                    bf[j] = *(const bfrag_t*)(w3p + (((rr - 1) * 8 + kc) * 2 + j) * 512);
#pragma unroll
                for (int i = 0; i < 4; ++i)
                    if (i < NI)
                        af[i] = *(const bfrag_t*)(Us + kc * 2048 + i * 512 + aoff);
#pragma unroll
                for (int i = 0; i < 4; ++i)
                    if (i < NI)
#pragma unroll
                        for (int j = 0; j < 2; ++j)
                            accO[i][j] = __builtin_amdgcn_mfma_f32_16x16x32_bf16(
                                af[i], bf[j], accO[i][j], 0, 0, 0);
            }
        }
        // tv prefetch for rr (used in u-pass; hidden under 2a MFMA)
        const int shift = shiftOf(rr);
        u32x4 tvreg[4];
#pragma unroll
        for (int q = 0; q < 4; ++q)
            if (q < NI) tvreg[q] = *(const u32x4*)(xtp + roffs[q] + shift);
        // 2a: z = h1 @ W2slab (reads As)
#pragma unroll
        for (int i = 0; i < 4; ++i)
#pragma unroll
            for (int j = 0; j < 2; ++j) acc[i][j] = (accfrag_t)0.f;
        const u16* w2p = w2base + rr * 8 * 8192;
#pragma unroll
        for (int kc = 0; kc < 8; ++kc) {
            bfrag_t bf[2], af[4];
#pragma unroll
            for (int j = 0; j < 2; ++j)
                bf[j] = *(const bfrag_t*)(w2p + (kc * 2 + j) * 512);
#pragma unroll
            for (int i = 0; i < 4; ++i)
                if (i < NI)
                    af[i] = *(const bfrag_t*)(As + kc * 2048 + i * 512 + aoff);
#pragma unroll
            for (int i = 0; i < 4; ++i)
                if (i < NI)
#pragma unroll
                    for (int j = 0; j < 2; ++j)
                        acc[i][j] = __builtin_amdgcn_mfma_f32_16x16x32_bf16(
                            af[i], bf[j], acc[i][j], 0, 0, 0);
        }
        __builtin_amdgcn_s_setprio(0);
        __syncthreads();  // all waves' 2b(rr-1) reads of Us done
        // sigmoid pair-pack -> Us slab `wave` (swizzled)
#pragma unroll
        for (int i = 0; i < 4; ++i) {
            if (i >= NI) continue;
#pragma unroll
            for (int j = 0; j < 2; ++j) {
                const float bv = b2p[rr * 256 + wave * 32 + j * 16 + fr];
#pragma unroll
                for (int r = 0; r < 4; ++r) {
                    const float z = acc[i][j][r] + bv;
                    const float s = __builtin_amdgcn_rcpf(1.f + __expf(-z));
                    const float sh = __shfl_down(s, 1);
                    if (!(lane & 1))
                        *(u32*)&Us[wave * 2048 + ewidx(i, j, r)] = pkbf16(s, sh);
                }
            }
        }
        // u = t * s in place; this wave's own slab chunks (no barrier:
        // same-wave LDS RAW, compiler-inserted lgkmcnt orders it)
#pragma unroll
        for (int q = 0; q < 4; ++q) {
            if (q >= NI) continue;
            u32x4 sv = *(const u32x4*)(Us + ldst[q]);
            u32x4 rv;
#pragma unroll
            for (int e = 0; e < 4; ++e)
                rv[e] = pkbf16(blo(sv[e]) * blo(tvreg[q][e]),
                               bhi(sv[e]) * bhi(tvreg[q][e]));
            *(u32x4*)(Us + ldst[q]) = rv;
        }
        __syncthreads();  // u visible to all waves
    }
    // final 2b for rr = 8
    __builtin_amdgcn_s_setprio(1);
#pragma unroll
    for (int kc = 0; kc < 8; ++kc) {
        bfrag_t bf[2], af[4];
#pragma unroll
        for (int j = 0; j < 2; ++j)
            bf[j] = *(const bfrag_t*)(w3p + ((8 * 8 + kc) * 2 + j) * 512);
#pragma unroll
        for (int i = 0; i < 4; ++i)
            if (i < NI)
                af[i] = *(const bfrag_t*)(Us + kc * 2048 + i * 512 + aoff);
#pragma unroll
        for (int i = 0; i < 4; ++i)
            if (i < NI)
#pragma unroll
                for (int j = 0; j < 2; ++j)
                    accO[i][j] = __builtin_amdgcn_mfma_f32_16x16x32_bf16(
                        af[i], bf[j], accO[i][j], 0, 0, 0);
    }
    __builtin_amdgcn_s_setprio(0);

    // ---------------- final epilogue: out = accO + b3 ----------------
#pragma unroll
    for (int i = 0; i < 4; ++i) {
        if (i >= NI) continue;
#pragma unroll
        for (int j = 0; j < 2; ++j) {
            const int col = wave * 32 + j * 16 + fr;
            const float bv = b3[col];
#pragma unroll
            for (int r = 0; r < 4; ++r) {
                const float v = accO[i][j][r] + bv;
                const float vh = __shfl_down(v, 1);
                if (!(lane & 1)) {
                    float2 st = make_float2(v, vh);
                    *(float2*)(out + (size_t)(l0 + i * 16 + fq * 4 + r) * 256 + col) = st;
                }
            }
        }
    }
}

extern "C" void kernel_launch(void* const* d_in, const int* in_sizes, int n_in,
                              void* d_out, int out_size, void* d_ws, size_t ws_size,
                              hipStream_t stream) {
    const float* x  = (const float*)d_in[0];
    const float* W1 = (const float*)d_in[1];
    const float* b1 = (const float*)d_in[2];
    const float* W2 = (const float*)d_in[3];
    const float* b2 = (const float*)d_in[4];
    const float* W3 = (const float*)d_in[5];
    const float* b3 = (const float*)d_in[6];
    float* out = (float*)d_out;

    char* ws = (char*)d_ws;
    u16* xtp = (u16*)ws;  ws += (size_t)8 * 58 * 58 * 256 * 2;
    u16* W1f = (u16*)ws;  ws += (size_t)589824 * 2;
    u16* W2f = (u16*)ws;  ws += (size_t)589824 * 2;
    u16* W3f = (u16*)ws;  ws += (size_t)589824 * 2;
    float* b2p = (float*)ws;

    k_prep<<<1153, 256, 0, stream>>>(x, W1, W2, W3, b2, xtp, W1f, W2f, W3f, b2p);
    k_fused<<<512, 512, 0, stream>>>(xtp, W1f, W2f, W3f, b1, b2p, b3, out);
}

// Round 11
// 199.309 us; speedup vs baseline: 1.1402x; 1.1402x over previous
//
#include <hip/hip_runtime.h>

typedef unsigned short u16;
typedef unsigned int u32;
typedef __attribute__((ext_vector_type(8))) short bfrag_t;   // 8 bf16 (4 VGPRs)
typedef __attribute__((ext_vector_type(4))) float accfrag_t; // 4 fp32
typedef __attribute__((ext_vector_type(4))) u32 u32x4;

// ---------- bf16 helpers ----------
__device__ __forceinline__ u16 f2b(float f) {
    u32 u = __float_as_uint(f);
    u32 r = (u + 0x7FFFu + ((u >> 16) & 1u)) >> 16;
    return (u16)r;
}
// pack 2 f32 -> 2 bf16 in one instruction (lo -> bits[15:0], hi -> bits[31:16])
__device__ __forceinline__ u32 pkbf16(float lo, float hi) {
    u32 r;
    asm("v_cvt_pk_bf16_f32 %0, %1, %2" : "=v"(r) : "v"(lo), "v"(hi));
    return r;
}
__device__ __forceinline__ float blo(u32 v) { return __uint_as_float(v << 16); }
__device__ __forceinline__ float bhi(u32 v) { return __uint_as_float(v & 0xffff0000u); }

// ---------- async global->LDS, 16B per lane ----------
__device__ __forceinline__ void load16(const u16* g, u16* l) {
    __builtin_amdgcn_global_load_lds(
        (__attribute__((address_space(1))) void*)(u16*)g,
        (__attribute__((address_space(3))) void*)l,
        16, 0, 0);
}

// ============================================================
// Merged prep: range dispatch, 1153 blocks. (identical since R2; R8
// probe measured its marginal cost at ~2 us — not a lever.)
// ============================================================
__global__ __launch_bounds__(256) void k_prep(
    const float* __restrict__ x, const float* __restrict__ W1,
    const float* __restrict__ W2, const float* __restrict__ W3,
    const float* __restrict__ b2, u16* __restrict__ xtp,
    u16* __restrict__ W1f, u16* __restrict__ W2f,
    u16* __restrict__ W3f, float* __restrict__ b2p) {
    __shared__ __align__(16) char smem[29184];
    const int bid = blockIdx.x;
    const int tid = threadIdx.x;
    if (bid < 928) {             // ---- xtp ----
        const int b = bid / 116;
        const int r = bid - b * 116;
        const int hp = r >> 1;           // 0..57
        const int ch = r & 1;            // c-half: c0 = ch*128
        u16* rowbase = xtp + (size_t)(b * 58 + hp) * 58 * 256;
        if (hp == 0 || hp == 57) {       // zero border row (ch==0 does it all)
            if (ch == 0) {
                u32* p = (u32*)rowbase;
                for (int i = tid; i < 58 * 128; i += 256) p[i] = 0;
            }
            return;
        }
        float* lds = (float*)smem;       // [cl:128][w:57]  (odd stride: conflict-free)
        const int h = hp - 1;
        const int c0 = ch * 128;
        const float* xb = x + (size_t)(b * 256 + c0) * 3136 + h * 56;
#pragma unroll
        for (int it = 0; it < 7; ++it) {
            const int idx = it * 256 + tid;
            const int cl = idx / 14;
            const int f4 = idx - cl * 14;
            const float4 v = *(const float4*)(xb + (size_t)cl * 3136 + f4 * 4);
            float* d = lds + cl * 57 + f4 * 4;
            d[0] = v.x; d[1] = v.y; d[2] = v.z; d[3] = v.w;
        }
        __syncthreads();
        u32* orow = (u32*)rowbase;
        const int cp = tid & 63;
        const int wg = tid >> 6;
        const float* l0p = lds + (2 * cp) * 57;
        const float* l1p = lds + (2 * cp + 1) * 57;
#pragma unroll
        for (int it = 0; it < 15; ++it) {
            const int wp = it * 4 + wg;  // 0..59
            if (wp < 58) {
                u32 val = 0;
                if (wp >= 1 && wp <= 56) val = pkbf16(l0p[wp - 1], l1p[wp - 1]);
                orow[wp * 128 + ch * 64 + cp] = val;
            }
        }
    } else if (bid < 1072) {     // ---- W1 / W3 pack ----
        int b = bid - 928;
        const float* in = b < 72 ? W1 : W3;
        u16* out = b < 72 ? W1f : W3f;
        if (b >= 72) b -= 72;
        const int rrp = b >> 3;          // 0..8
        const int cg = b & 7;            // c-group of 32
        u16* lds1 = (u16*)smem;          // [q:32][n:256]
#pragma unroll
        for (int cc = 0; cc < 32; ++cc) {
            int d = (cg * 32 + cc) * 9 + rrp;
            lds1[cc * 256 + tid] = f2b(in[d * 256 + tid]);
        }
        __syncthreads();
        const int kc72 = rrp * 8 + cg;
#pragma unroll
        for (int s = 0; s < 32; ++s) {
            const int w = s >> 2;
            const int o = (s & 3) * 256 + tid;    // 0..1023 within [j][lane][e]
            const int e = o & 7;
            const int ln = (o >> 3) & 63;
            const int j = o >> 9;
            const int n = w * 32 + j * 16 + (ln & 15);
            const int q = (ln >> 4) * 8 + e;
            out[(w * 72 + kc72) * 1024 + o] = lds1[q * 256 + n];
        }
    } else if (bid < 1144) {     // ---- W2 pack ----
        const int b = bid - 1072;
        const int rr = b >> 3;
        const int w = b & 7;
        u16* lds2 = (u16*)smem;          // [k:256][dloc:32]
#pragma unroll
        for (int s = 0; s < 32; ++s) {
            int li = s * 256 + tid;
            int k = li >> 5, dloc = li & 31;
            lds2[k * 32 + dloc] = f2b(W2[k * 2304 + (w * 32 + dloc) * 9 + rr]);
        }
        __syncthreads();
        u16* ob = W2f + (rr * 8 + w) * 8192;
#pragma unroll
        for (int s = 0; s < 32; ++s) {
            const int o = s * 256 + tid;          // 0..8191
            const int e = o & 7;
            const int ln = (o >> 3) & 63;
            const int j = (o >> 9) & 1;
            const int kc = o >> 10;
            const int k = kc * 32 + (ln >> 4) * 8 + e;
            const int dloc = j * 16 + (ln & 15);
            ob[o] = lds2[k * 32 + dloc];
        }
    } else {                     // ---- b2 permute ----
        int idx = (bid - 1144) * 256 + tid;
        if (idx < 2304) b2p[idx] = b2[(idx & 255) * 9 + (idx >> 8)];
    }
}

// ============================================================
// Fused kernel v8 (RESTORED — best measured: 127.0 us, total 201.1).
// 392x512, 1x8 col split, swizzled LDS (0 conflicts), wave=kc slab
// ownership (same-wave sigmoid->u, no barrier), merged [2b(rr-1);2a(rr)]
// region (2 barriers/rr), setprio, T1 XCD-chunk swizzle (FETCH 52->22MB).
// v9's 512-block balanced grid REVERTED: +30% per-XCD L2 weight stream
// (block-proportional) overwhelmed the -12.5% row-balance gain and
// thrashed L2 (FETCH 108MB). Structural plateau: MFMA 36 + LDS 49 +
// L2 weights 50 + VALU 32 ~= 167us of pipe work overlapping into 127us;
// register file (4w x 128 regs), LDS (64KB x 2 blocks), occupancy and
// block count all at measured walls (v4/v5/v7/v9 probes).
// ============================================================
__global__ __launch_bounds__(512, 4) void k_fused(
    const u16* __restrict__ xtp, const u16* __restrict__ W1f,
    const u16* __restrict__ W2f, const u16* __restrict__ W3f,
    const float* __restrict__ b1, const float* __restrict__ b2p,
    const float* __restrict__ b3, float* __restrict__ out) {
    __shared__ __align__(16) u16 As[16384];  // 32KB: t-slab buf0, then h1 [kc:8][row:64][slot:4][8]
    __shared__ __align__(16) u16 Us[16384];  // 32KB: t-slab buf1, then s/u same layout

    const int tid = threadIdx.x;
    const int wave = tid >> 6;
    const int lane = tid & 63;
    const int fr = lane & 15;
    const int fq = lane >> 4;
    // T1 XCD swizzle (bijective: 392 % 8 == 0): XCD k gets blocks k*49..k*49+48
    const int bid = (blockIdx.x % 8) * 49 + (blockIdx.x / 8);
    const int l0 = bid * 64;

    // ---- wave=kc ownership: wave w stages/owns slab w ----
    const int swz = (lane & 3) ^ ((lane >> 3) & 3);
    int roffs[4], ldst[4];
#pragma unroll
    for (int q = 0; q < 4; ++q) {
        const int row = q * 16 + (lane >> 2);
        const int l = l0 + row;
        const int b = l / 3136;
        const int rem = l - b * 3136;
        const int h = rem / 56;
        const int w = rem - h * 56;
        roffs[q] = ((b * 58 + h + 1) * 58 + (w + 1)) * 256 + wave * 32 + swz * 8;
        ldst[q] = wave * 2048 + (q * 64 + lane) * 8;
    }
    // A-frag read offset within a kc-slab: row=i*16+fr, slot=fq^((fr>>1)&3)
    const int aoff = fr * 32 + ((fq ^ ((fr >> 1) & 3)) * 8);
    auto shiftOf = [](int rr) { return ((rr / 3 - 1) * 58 + (rr % 3) - 1) * 256; };
    auto stage = [&](u16* buf, int shift) {
#pragma unroll
        for (int q = 0; q < 4; ++q)
            load16(xtp + roffs[q] + shift, buf + ldst[q]);
    };
    // swizzled epilogue u32-write index (u16 units) within slab `wave`
    auto ewidx = [&](int i, int j, int r) {
        const int row = i * 16 + fq * 4 + r;
        const int sl = (j * 2 + (fr >> 3)) ^ ((fq * 2 + (r >> 1)) & 3);
        return row * 32 + sl * 8 + (fr & 7);
    };

    accfrag_t acc[4][2], accO[4][2];
#pragma unroll
    for (int i = 0; i < 4; ++i)
#pragma unroll
        for (int j = 0; j < 2; ++j) {
            acc[i][j] = (accfrag_t)0.f;
            accO[i][j] = (accfrag_t)0.f;
        }

    // ---------------- phase 1: h1 = relu(t @ W1 + b1), double-buffered ----
    const u16* w1p = W1f + wave * 73728 + lane * 8;
    stage(As, shiftOf(0));
    for (int rr = 0; rr < 9; ++rr) {
        u16* cur = (rr & 1) ? Us : As;
        u16* nxt = (rr & 1) ? As : Us;
        __syncthreads();   // cur slab visible (and nxt's readers from rr-1 done)
        if (rr < 8) stage(nxt, shiftOf(rr + 1));   // in flight during MFMA
        __builtin_amdgcn_s_setprio(1);
#pragma unroll
        for (int kc = 0; kc < 8; ++kc) {
            bfrag_t bf[2], af[4];
#pragma unroll
            for (int j = 0; j < 2; ++j)
                bf[j] = *(const bfrag_t*)(w1p + ((rr * 8 + kc) * 2 + j) * 512);
#pragma unroll
            for (int i = 0; i < 4; ++i)
                af[i] = *(const bfrag_t*)(cur + kc * 2048 + i * 512 + aoff);
#pragma unroll
            for (int i = 0; i < 4; ++i)
#pragma unroll
                for (int j = 0; j < 2; ++j)
                    acc[i][j] = __builtin_amdgcn_mfma_f32_16x16x32_bf16(
                        af[i], bf[j], acc[i][j], 0, 0, 0);
        }
        __builtin_amdgcn_s_setprio(0);
    }
    // h1 epilogue: relu, pair-pack (cvt_pk), into As slab `wave` (swizzled)
    __syncthreads();
#pragma unroll
    for (int i = 0; i < 4; ++i) {
#pragma unroll
        for (int j = 0; j < 2; ++j) {
            const float bv = b1[wave * 32 + j * 16 + fr];
#pragma unroll
            for (int r = 0; r < 4; ++r) {
                float v = acc[i][j][r] + bv;
                v = v > 0.f ? v : 0.f;
                const float vh = __shfl_down(v, 1);
                if (!(lane & 1))
                    *(u32*)&As[wave * 2048 + ewidx(i, j, r)] = pkbf16(v, vh);
            }
        }
    }
    __syncthreads();  // h1 visible to all waves

    // ---------------- phase 2: pipelined per-rr ----------------
    // per rr: [2b(rr-1); 2a(rr)]  barrier  [sigmoid; u(same-wave)]  barrier
    const u16* w3p = W3f + wave * 73728 + lane * 8;
    const u16* w2base = W2f + (wave)*8192 + lane * 8;  // + rr*8*8192 per rr
    for (int rr = 0; rr < 9; ++rr) {
        // 2b for rr-1 (reads Us; no Us writes since last barrier)
        __builtin_amdgcn_s_setprio(1);
        if (rr > 0) {
#pragma unroll
            for (int kc = 0; kc < 8; ++kc) {
                bfrag_t bf[2], af[4];
#pragma unroll
                for (int j = 0; j < 2; ++j)
                    bf[j] = *(const bfrag_t*)(w3p + (((rr - 1) * 8 + kc) * 2 + j) * 512);
#pragma unroll
                for (int i = 0; i < 4; ++i)
                    af[i] = *(const bfrag_t*)(Us + kc * 2048 + i * 512 + aoff);
#pragma unroll
                for (int i = 0; i < 4; ++i)
#pragma unroll
                    for (int j = 0; j < 2; ++j)
                        accO[i][j] = __builtin_amdgcn_mfma_f32_16x16x32_bf16(
                            af[i], bf[j], accO[i][j], 0, 0, 0);
            }
        }
        // tv prefetch for rr (used in u-pass; hidden under 2a MFMA)
        const int shift = shiftOf(rr);
        u32x4 tvreg[4];
#pragma unroll
        for (int q = 0; q < 4; ++q)
            tvreg[q] = *(const u32x4*)(xtp + roffs[q] + shift);
        // 2a: z = h1 @ W2slab (reads As)
#pragma unroll
        for (int i = 0; i < 4; ++i)
#pragma unroll
            for (int j = 0; j < 2; ++j) acc[i][j] = (accfrag_t)0.f;
        const u16* w2p = w2base + rr * 8 * 8192;
#pragma unroll
        for (int kc = 0; kc < 8; ++kc) {
            bfrag_t bf[2], af[4];
#pragma unroll
            for (int j = 0; j < 2; ++j)
                bf[j] = *(const bfrag_t*)(w2p + (kc * 2 + j) * 512);
#pragma unroll
            for (int i = 0; i < 4; ++i)
                af[i] = *(const bfrag_t*)(As + kc * 2048 + i * 512 + aoff);
#pragma unroll
            for (int i = 0; i < 4; ++i)
#pragma unroll
                for (int j = 0; j < 2; ++j)
                    acc[i][j] = __builtin_amdgcn_mfma_f32_16x16x32_bf16(
                        af[i], bf[j], acc[i][j], 0, 0, 0);
        }
        __builtin_amdgcn_s_setprio(0);
        __syncthreads();  // all waves' 2b(rr-1) reads of Us done
        // sigmoid pair-pack -> Us slab `wave` (swizzled)
#pragma unroll
        for (int i = 0; i < 4; ++i) {
#pragma unroll
            for (int j = 0; j < 2; ++j) {
                const float bv = b2p[rr * 256 + wave * 32 + j * 16 + fr];
#pragma unroll
                for (int r = 0; r < 4; ++r) {
                    const float z = acc[i][j][r] + bv;
                    const float s = __builtin_amdgcn_rcpf(1.f + __expf(-z));
                    const float sh = __shfl_down(s, 1);
                    if (!(lane & 1))
                        *(u32*)&Us[wave * 2048 + ewidx(i, j, r)] = pkbf16(s, sh);
                }
            }
        }
        // u = t * s in place; this wave's own slab chunks (no barrier:
        // same-wave LDS RAW, compiler-inserted lgkmcnt orders it)
#pragma unroll
        for (int q = 0; q < 4; ++q) {
            u32x4 sv = *(const u32x4*)(Us + ldst[q]);
            u32x4 rv;
#pragma unroll
            for (int e = 0; e < 4; ++e)
                rv[e] = pkbf16(blo(sv[e]) * blo(tvreg[q][e]),
                               bhi(sv[e]) * bhi(tvreg[q][e]));
            *(u32x4*)(Us + ldst[q]) = rv;
        }
        __syncthreads();  // u visible to all waves
    }
    // final 2b for rr = 8
    __builtin_amdgcn_s_setprio(1);
#pragma unroll
    for (int kc = 0; kc < 8; ++kc) {
        bfrag_t bf[2], af[4];
#pragma unroll
        for (int j = 0; j < 2; ++j)
            bf[j] = *(const bfrag_t*)(w3p + ((8 * 8 + kc) * 2 + j) * 512);
#pragma unroll
        for (int i = 0; i < 4; ++i)
            af[i] = *(const bfrag_t*)(Us + kc * 2048 + i * 512 + aoff);
#pragma unroll
        for (int i = 0; i < 4; ++i)
#pragma unroll
            for (int j = 0; j < 2; ++j)
                accO[i][j] = __builtin_amdgcn_mfma_f32_16x16x32_bf16(
                    af[i], bf[j], accO[i][j], 0, 0, 0);
    }
    __builtin_amdgcn_s_setprio(0);

    // ---------------- final epilogue: out = accO + b3 ----------------
#pragma unroll
    for (int i = 0; i < 4; ++i) {
#pragma unroll
        for (int j = 0; j < 2; ++j) {
            const int col = wave * 32 + j * 16 + fr;
            const float bv = b3[col];
#pragma unroll
            for (int r = 0; r < 4; ++r) {
                const float v = accO[i][j][r] + bv;
                const float vh = __shfl_down(v, 1);
                if (!(lane & 1)) {
                    float2 st = make_float2(v, vh);
                    *(float2*)(out + (size_t)(l0 + i * 16 + fq * 4 + r) * 256 + col) = st;
                }
            }
        }
    }
}

extern "C" void kernel_launch(void* const* d_in, const int* in_sizes, int n_in,
                              void* d_out, int out_size, void* d_ws, size_t ws_size,
                              hipStream_t stream) {
    const float* x  = (const float*)d_in[0];
    const float* W1 = (const float*)d_in[1];
    const float* b1 = (const float*)d_in[2];
    const float* W2 = (const float*)d_in[3];
    const float* b2 = (const float*)d_in[4];
    const float* W3 = (const float*)d_in[5];
    const float* b3 = (const float*)d_in[6];
    float* out = (float*)d_out;

    char* ws = (char*)d_ws;
    u16* xtp = (u16*)ws;  ws += (size_t)8 * 58 * 58 * 256 * 2;
    u16* W1f = (u16*)ws;  ws += (size_t)589824 * 2;
    u16* W2f = (u16*)ws;  ws += (size_t)589824 * 2;
    u16* W3f = (u16*)ws;  ws += (size_t)589824 * 2;
    float* b2p = (float*)ws;

    k_prep<<<1153, 256, 0, stream>>>(x, W1, W2, W3, b2, xtp, W1f, W2f, W3f, b2p);
    k_fused<<<392, 512, 0, stream>>>(xtp, W1f, W2f, W3f, b1, b2p, b3, out);
}